// Round 2
// baseline (218.685 us; speedup 1.0000x reference)
//
#include <hip/hip_runtime.h>
#include <hip/hip_bf16.h>
#include <math.h>

#define B_   8
#define C_   192
#define N_   3136
#define K_   9
#define OUT_ 384
#define G_   4
#define CG_  96   // in-channels per group (2C/G)
#define OG_  96   // out-channels per group
#define NT_  32   // n-rows per fused block
#define LDW  196  // LDS row width in dwords (192 data + 4 pad)

typedef __attribute__((ext_vector_type(8))) short short8;
typedef __attribute__((ext_vector_type(4))) float floatx4;

// ---------------- ws layout (bytes) ----------------
// xT : B*N*C   bf16 =  9,633,792
// y  : B*OUT*N bf16 = 19,267,584
// st : OUT*2   f32  =      3,072
static const size_t OFF_XT = 0;
static const size_t OFF_Y  = 9633792;
static const size_t OFF_ST = OFF_Y + 19267584;

__device__ inline short f2bs(float f) {
    __hip_bfloat16 h = __float2bfloat16(f);
    union { __hip_bfloat16 h; short s; } u; u.h = h; return u.s;
}
__device__ inline float blo(unsigned int u) {
    unsigned int v = u << 16; return __builtin_bit_cast(float, v);
}
__device__ inline float bhi(unsigned int u) {
    unsigned int v = u & 0xffff0000u; return __builtin_bit_cast(float, v);
}
__device__ inline unsigned int packbf(float lo, float hi) {
    unsigned int l = (unsigned int)(unsigned short)f2bs(lo);
    unsigned int h = (unsigned int)(unsigned short)f2bs(hi);
    return (h << 16) | l;
}

// ---- Kernel A: transpose x [B,C,N] f32 -> xT [B,N,C] bf16; zero BN accum ----
__global__ __launch_bounds__(256) void k_transpose(const float* __restrict__ x,
                                                   __hip_bfloat16* __restrict__ xT,
                                                   float* __restrict__ st) {
    if (blockIdx.x == 0 && blockIdx.y == 0 && blockIdx.z == 0) {
        #pragma unroll
        for (int i = 0; i < 3; ++i) st[threadIdx.x + i * 256] = 0.0f;
    }
    __shared__ float tile[64][65];
    int b  = blockIdx.x;
    int cb = blockIdx.y * 64;
    int nb = blockIdx.z * 64;
    int tid = threadIdx.x;
    int tn  = tid & 63;
    int tc4 = tid >> 6;
    const float* xp = x + ((size_t)b * C_ + cb) * N_ + nb;
    #pragma unroll
    for (int i = 0; i < 16; ++i) {
        int c = tc4 + i * 4;
        tile[c][tn] = xp[(size_t)c * N_ + tn];
    }
    __syncthreads();
    __hip_bfloat16* xo = xT + ((size_t)b * N_ + nb) * C_ + cb;
    int tcl = tid & 63;
    int tn4 = tid >> 6;
    #pragma unroll
    for (int i = 0; i < 16; ++i) {
        int n = tn4 + i * 4;
        xo[(size_t)n * C_ + tcl] = __float2bfloat16(tile[tcl][n]);
    }
}

// ---- Kernel B: fused gather + max-rel (LDS) + grouped MFMA conv + BN stats ----
__global__ __launch_bounds__(256) void k_fused(const __hip_bfloat16* __restrict__ xT,
                                               const int* __restrict__ eidx,
                                               const float* __restrict__ conv_w,
                                               const float* __restrict__ bias,
                                               __hip_bfloat16* __restrict__ y,
                                               float* __restrict__ st) {
    int b  = blockIdx.x;
    int n0 = blockIdx.y * NT_;
    int lane = threadIdx.x & 63;
    int g    = threadIdx.x >> 6;          // wave id == conv group
    int col  = lane & 15;
    int quad = lane >> 4;

    __shared__ unsigned int xcs[NT_ * LDW];   // 25,088 B: xc tile, interleaved [n][2C]

    // --- weight fragments: fp32 -> bf16 in-register (L2-resident W) ---
    short8 wf[3][6];
    #pragma unroll
    for (int mt = 0; mt < 6; ++mt) {
        #pragma unroll
        for (int kc = 0; kc < 3; ++kc) {
            const float* wp = conv_w + (size_t)(g * OG_ + mt * 16 + col) * CG_ + kc * 32 + quad * 8;
            float4 w0 = *reinterpret_cast<const float4*>(wp);
            float4 w1 = *reinterpret_cast<const float4*>(wp + 4);
            short8 v;
            v[0] = f2bs(w0.x); v[1] = f2bs(w0.y); v[2] = f2bs(w0.z); v[3] = f2bs(w0.w);
            v[4] = f2bs(w1.x); v[5] = f2bs(w1.y); v[6] = f2bs(w1.z); v[7] = f2bs(w1.w);
            wf[kc][mt] = v;
        }
    }

    // --- gather + max-relative into LDS ---
    const __hip_bfloat16* xb = xT + (size_t)b * N_ * C_;
    int rhalf = lane >> 5;     // which row of the pair
    int cd    = lane & 31;     // channel-dword index base
    #pragma unroll
    for (int p = 0; p < 4; ++p) {
        int rl = g * 8 + p * 2 + rhalf;   // local row 0..31
        int n  = n0 + rl;
        const int* e0 = eidx + ((size_t)b * N_ + n) * K_;                        // x_j idx
        const int* e1 = eidx + (size_t)B_ * N_ * K_ + ((size_t)b * N_ + n) * K_; // x_i idx
        int j0[K_], j1[K_];
        #pragma unroll
        for (int k = 0; k < K_; ++k) { j0[k] = e0[k]; j1[k] = e1[k]; }
        const unsigned int* xnrow = reinterpret_cast<const unsigned int*>(xb + (size_t)n * C_);
        #pragma unroll
        for (int it = 0; it < 3; ++it) {
            int c2 = cd + it * 32;        // dword idx within 96 (channels 2c2, 2c2+1)
            unsigned int ctr = xnrow[c2];
            float r0 = -INFINITY, r1 = -INFINITY;
            #pragma unroll
            for (int k = 0; k < K_; ++k) {
                unsigned int uj = reinterpret_cast<const unsigned int*>(xb + (size_t)j0[k] * C_)[c2];
                unsigned int ui = reinterpret_cast<const unsigned int*>(xb + (size_t)j1[k] * C_)[c2];
                r0 = fmaxf(r0, blo(uj) - blo(ui));
                r1 = fmaxf(r1, bhi(uj) - bhi(ui));
            }
            uint2 o;
            o.x = packbf(blo(ctr), r0);   // elems 4c2, 4c2+1  : x_{2c2}, rel_{2c2}
            o.y = packbf(bhi(ctr), r1);   // elems 4c2+2,4c2+3 : x_{2c2+1}, rel_{2c2+1}
            *reinterpret_cast<uint2*>(&xcs[(size_t)rl * LDW + 2 * c2]) = o;
        }
    }
    __syncthreads();

    // --- MFMA: A = W_g [96 oc x 96 k], B = xc tile [96 k x 32 n] ---
    floatx4 acc[6][2];
    #pragma unroll
    for (int mt = 0; mt < 6; ++mt) {
        acc[mt][0] = (floatx4){0.f, 0.f, 0.f, 0.f};
        acc[mt][1] = (floatx4){0.f, 0.f, 0.f, 0.f};
    }
    #pragma unroll
    for (int h = 0; h < 2; ++h) {
        int row = h * 16 + col;
        const short* rp = reinterpret_cast<const short*>(&xcs[(size_t)row * LDW]);
        short8 bfr[3];
        #pragma unroll
        for (int kc = 0; kc < 3; ++kc)
            bfr[kc] = *reinterpret_cast<const short8*>(rp + g * CG_ + kc * 32 + quad * 8);
        #pragma unroll
        for (int kc = 0; kc < 3; ++kc)
            #pragma unroll
            for (int mt = 0; mt < 6; ++mt)
                acc[mt][h] = __builtin_amdgcn_mfma_f32_16x16x32_bf16(wf[kc][mt], bfr[kc], acc[mt][h], 0, 0, 0);
    }

    // --- epilogue: bias, y write (bf16), BN partial stats from fp32 acc ---
    #pragma unroll
    for (int mt = 0; mt < 6; ++mt) {
        #pragma unroll
        for (int r = 0; r < 4; ++r) {
            int oc = g * OG_ + mt * 16 + quad * 4 + r;
            float bv = bias[oc];
            float v0 = acc[mt][0][r] + bv;
            float v1 = acc[mt][1][r] + bv;
            size_t yb = (size_t)(b * OUT_ + oc) * N_ + n0;
            y[yb + col]      = __float2bfloat16(v0);
            y[yb + 16 + col] = __float2bfloat16(v1);
            float s  = v0 + v1;
            float ss = v0 * v0 + v1 * v1;
            #pragma unroll
            for (int m = 1; m <= 8; m <<= 1) {
                s  += __shfl_xor(s, m);
                ss += __shfl_xor(ss, m);
            }
            if (col == 0) {
                atomicAdd(&st[oc], s);
                atomicAdd(&st[OUT_ + oc], ss);
            }
        }
    }
}

// ---- Kernel C: BN (batch stats) + exact GELU, write fp32 out [B,OUT,N] ----
__global__ __launch_bounds__(256) void k_bn_gelu(const __hip_bfloat16* __restrict__ y,
                                                 const float* __restrict__ st,
                                                 const float* __restrict__ gamma,
                                                 const float* __restrict__ beta,
                                                 float* __restrict__ out) {
    size_t base = ((size_t)blockIdx.x * 256 + threadIdx.x) * 4;
    int oc = (int)((base / N_) % OUT_);
    const float invM = 1.0f / (float)(B_ * N_);
    float s = st[oc], ss = st[OUT_ + oc];
    float mean = s * invM;
    float var  = ss * invM - mean * mean;
    float inv  = 1.0f / sqrtf(var + 1e-5f);
    float sc = gamma[oc] * inv;
    float sh = beta[oc] - mean * sc;

    const __hip_bfloat162* yp = reinterpret_cast<const __hip_bfloat162*>(y + base);
    __hip_bfloat162 p0 = yp[0], p1 = yp[1];
    float v[4] = { __bfloat162float(p0.x), __bfloat162float(p0.y),
                   __bfloat162float(p1.x), __bfloat162float(p1.y) };
    float4 o;
    float* op = &o.x;
    #pragma unroll
    for (int j = 0; j < 4; ++j) {
        float t = v[j] * sc + sh;
        op[j] = 0.5f * t * (1.0f + erff(t * 0.70710678118654752f));
    }
    *reinterpret_cast<float4*>(out + base) = o;
}

extern "C" void kernel_launch(void* const* d_in, const int* in_sizes, int n_in,
                              void* d_out, int out_size, void* d_ws, size_t ws_size,
                              hipStream_t stream) {
    const float* x      = (const float*)d_in[0];
    const int*   eidx   = (const int*)d_in[1];
    const float* conv_w = (const float*)d_in[2];
    const float* conv_b = (const float*)d_in[3];
    const float* gamma  = (const float*)d_in[4];
    const float* beta   = (const float*)d_in[5];
    float* out = (float*)d_out;

    char* ws = (char*)d_ws;
    __hip_bfloat16* xT = (__hip_bfloat16*)(ws + OFF_XT);
    __hip_bfloat16* y  = (__hip_bfloat16*)(ws + OFF_Y);
    float*          st = (float*)(ws + OFF_ST);

    k_transpose<<<dim3(B_, C_ / 64, N_ / 64), 256, 0, stream>>>(x, xT, st);
    k_fused<<<dim3(B_, N_ / NT_), 256, 0, stream>>>(xT, eidx, conv_w, conv_b, y, st);
    k_bn_gelu<<<dim3((B_ * OUT_ * N_) / (256 * 4)), 256, 0, stream>>>(y, st, gamma, beta, out);
}